// Round 5
// baseline (350.563 us; speedup 1.0000x reference)
//
#include <hip/hip_runtime.h>
#include <hip/hip_bf16.h>
#include <stdint.h>

// ---------------------------------------------------------------------------
// HeadAttention: Q=xq*W^T+b, K=xk*W^T+b, V=xv*W^T+b (same W,b),
// O = softmax(causal(Q K^T / 32)) V.    B=4, S=2048, E=1024, fp32 in/out.
// R10: qkv+scores use a faithful m201-style 8-phase 256x256 kloop:
//   8 waves as 2(M)x4(N), per-wave 128x64, BK=64, 128KB LDS (2 slots).
//   Per K-tile 4 quadrant phases (snake (0,0),(0,1),(1,1),(1,0)); per phase:
//   {ds_reads (12/4/8/0); stage ONE 128x64 half-tile; s_barrier; lgkm0;
//    setprio(1); 16 MFMA; setprio(0); s_barrier}.
//   Staging schedule (slot = tile parity):
//     ph1 -> B-hi(t+1), ph2 -> A-hi(t+1), ph3 -> B-lo(t+2), ph4 -> A-lo(t+2)
//   Single counted vmcnt(4) at ph4 (retires ALL of t+1, keeps t+2-lo pair
//   in flight; 0 only for the last two tiles).
//   WAR safety: B-halves of tile x last read at ph2(x), A-halves at ph3(x);
//     ph1(t) overwrites B-hi(t-1) [read ended ph2(t-1)]  OK
//     ph2(t) overwrites A-hi(t-1) [ended ph3(t-1)]       OK
//     ph3(t) overwrites B-lo(t)   [ended ph2(t)+barrier] OK
//     ph4(t) overwrites A-lo(t)   [ended ph3(t)+barrier] OK
//   RAW: at ph4(t) the per-thread VMEM queue is [B-lo(t+1),A-lo(t+1),
//     B-hi(t+1),A-hi(t+1),B-lo(t+2),A-lo(t+2)] (12 loads); vmcnt(4) retires
//     the 8 oldest = all four halves of t+1, before any ph1(t+1) ds_read.
//   LDS layout: [256][64] bf16 rows (128B), chunk c of row r at slot
//   c^(r&7); linear global_load_lds dest + inverse-swizzled source
//   (R6-measured: SQ_LDS_BANK_CONFLICT == 0 for this exact read pattern).
// pv + cvt are the R5-proven kernels, unchanged.
// ---------------------------------------------------------------------------

typedef __attribute__((ext_vector_type(8))) short bf16x8;
typedef __attribute__((ext_vector_type(4))) float floatx4;

#define DEVI static __device__ __forceinline__

static constexpr int S_ = 2048;
static constexpr int E_ = 1024;
static constexpr int BATCH = 4;
static constexpr int N4X = 8192 * 1024 / 4;  // float4 count per X input

DEVI unsigned short f2b(float f) {
  union { float f; unsigned u; } v; v.f = f;
  return (unsigned short)((v.u + 0x7FFFu + ((v.u >> 16) & 1u)) >> 16); // RNE
}

DEVI void async_load16(const void* g, void* l) {
  __builtin_amdgcn_global_load_lds(
      (__attribute__((address_space(1))) void*)(void*)(g),
      (__attribute__((address_space(3))) void*)(l),
      16, 0, 0);
}

#define BAR asm volatile("s_barrier" ::: "memory")
#define LGKM0 asm volatile("s_waitcnt lgkmcnt(0)" ::: "memory")

// ---------------- 256x256 8-phase template machinery ----------------------

// read logical (row r in [0,256), k-chunk kslot) from a swizzled [256][64]
// tile: rows are 64 shorts (128B); chunk stored at slot kslot^(r&7).
DEVI bf16x8 ldfrag64(const unsigned short* ls, int r, int kslot) {
  return *(const bf16x8*)(ls + r * 64 + ((kslot ^ (r & 7)) << 3));
}

// stage one 128x64 half-tile (2 x 16B per thread, 512 threads); LDS dest
// linear, source chunk inverse-swizzled.
DEVI void stage_half(const unsigned short* __restrict__ src, int ld,
                     unsigned short* ls, int tid) {
#pragma unroll
  for (int j = 0; j < 2; ++j) {
    const int u = tid + j * 512;
    const int row = u >> 3, slot = u & 7;
    async_load16(src + (size_t)row * ld + ((slot ^ (row & 7)) << 3),
                 ls + u * 8);
  }
}

// one C-quadrant: 4(m) x 2(n) x 2(ksub) = 16 MFMA
DEVI void quad16(const bf16x8 (&af)[4][2], const bf16x8 (&bf)[2][2],
                 floatx4 (&acc)[8][4], int MB, int NB) {
  __builtin_amdgcn_s_setprio(1);
#pragma unroll
  for (int mi = 0; mi < 4; ++mi)
#pragma unroll
    for (int ni = 0; ni < 2; ++ni)
#pragma unroll
      for (int ks = 0; ks < 2; ++ks)
        acc[MB + mi][NB + ni] = __builtin_amdgcn_mfma_f32_16x16x32_bf16(
            af[mi][ks], bf[ni][ks], acc[MB + mi][NB + ni], 0, 0, 0);
  __builtin_amdgcn_s_setprio(0);
}

DEVI void kloop256(const unsigned short* __restrict__ A, int lda,
                   const unsigned short* __restrict__ Bm, int ldb, int NT,
                   unsigned short* lsA, unsigned short* lsB, int tid,
                   floatx4 (&acc)[8][4]) {
  constexpr int SL = 256 * 64;  // slot stride (shorts)
  constexpr int HH = 128 * 64;  // half-tile stride within a slot
  const int lane = tid & 63, g = lane >> 4, lr = lane & 15;
  const int wr = (tid >> 6) >> 2, wc = (tid >> 6) & 3;
  const int ar0 = wr * 128 + lr;  // A row base (sub-half 0)
  const int br0 = wc * 64 + lr;   // B row base (sub-half 0)

  // prologue: all of tile 0, plus lo-halves of tile 1
  stage_half(Bm, ldb, lsB, tid);                    // B-lo(0)
  stage_half(A, lda, lsA, tid);                     // A-lo(0)
  stage_half(Bm + (size_t)128 * ldb, ldb, lsB + HH, tid);  // B-hi(0)
  stage_half(A + (size_t)128 * lda, lda, lsA + HH, tid);   // A-hi(0)
  if (NT > 1) {
    stage_half(Bm + 64, ldb, lsB + SL, tid);        // B-lo(1)
    stage_half(A + 64, lda, lsA + SL, tid);         // A-lo(1)
    asm volatile("s_waitcnt vmcnt(4)" ::: "memory");
  } else {
    asm volatile("s_waitcnt vmcnt(0)" ::: "memory");
  }
  BAR;

  bf16x8 a[4][2], b0[2][2], b1[2][2];
  for (int t = 0; t < NT; ++t) {
    const int ps = (t & 1) * SL;       // slot of tile t
    const int qs = SL - ps;            // slot of tile t+1
    const unsigned short* la = lsA + ps;
    const unsigned short* lb = lsB + ps;
    // ---- ph1: quad (0,0); read A-sub0 (8) + B-sub0 (4) ----
#pragma unroll
    for (int mi = 0; mi < 4; ++mi)
#pragma unroll
      for (int ks = 0; ks < 2; ++ks)
        a[mi][ks] = ldfrag64(la, ar0 + mi * 16, g + ks * 4);
#pragma unroll
    for (int ni = 0; ni < 2; ++ni)
#pragma unroll
      for (int ks = 0; ks < 2; ++ks)
        b0[ni][ks] = ldfrag64(lb, br0 + ni * 16, g + ks * 4);
    if (t + 1 < NT)  // stage B-hi(t+1)
      stage_half(Bm + (size_t)128 * ldb + (t + 1) * 64, ldb, lsB + qs + HH,
                 tid);
    BAR; LGKM0;
    quad16(a, b0, acc, 0, 0);
    BAR;
    // ---- ph2: quad (0,1); read B-sub1 (4) ----
#pragma unroll
    for (int ni = 0; ni < 2; ++ni)
#pragma unroll
      for (int ks = 0; ks < 2; ++ks)
        b1[ni][ks] = ldfrag64(lb, br0 + 32 + ni * 16, g + ks * 4);
    if (t + 1 < NT)  // stage A-hi(t+1)
      stage_half(A + (size_t)128 * lda + (t + 1) * 64, lda, lsA + qs + HH,
                 tid);
    BAR; LGKM0;
    quad16(a, b1, acc, 0, 2);
    BAR;
    // ---- ph3: quad (1,1); read A-sub1 (8, reuse regs of a) ----
#pragma unroll
    for (int mi = 0; mi < 4; ++mi)
#pragma unroll
      for (int ks = 0; ks < 2; ++ks)
        a[mi][ks] = ldfrag64(la, ar0 + 64 + mi * 16, g + ks * 4);
    if (t + 2 < NT)  // stage B-lo(t+2) into slot ps (B(t) reads ended ph2)
      stage_half(Bm + (t + 2) * 64, ldb, lsB + ps, tid);
    BAR; LGKM0;
    quad16(a, b1, acc, 4, 2);
    BAR;
    // ---- ph4: quad (1,0); no reads ----
    if (t + 2 < NT)  // stage A-lo(t+2) into slot ps (A(t) reads ended ph3)
      stage_half(A + (t + 2) * 64, lda, lsA + ps, tid);
    if (t + 2 < NT) {
      asm volatile("s_waitcnt vmcnt(4)" ::: "memory");  // all of t+1 landed
    } else {
      asm volatile("s_waitcnt vmcnt(0)" ::: "memory");
    }
    BAR;
    quad16(a, b0, acc, 4, 0);
    BAR;
  }
}

// ---------------- R5 helpers (pv): 128x32 linear tiles ---------------------

DEVI void mfma_tile(const unsigned short* lsA, const unsigned short* lsB,
                    int m0, int n0, int lrow, int lk, floatx4 (&acc)[4][4]) {
  bf16x8 af[4], bfr[4];
#pragma unroll
  for (int i = 0; i < 4; ++i)
    af[i] = *(const bf16x8*)(lsA + (m0 + i * 16 + lrow) * 32 + lk);
#pragma unroll
  for (int i = 0; i < 4; ++i)
    bfr[i] = *(const bf16x8*)(lsB + (n0 + i * 16 + lrow) * 32 + lk);
#pragma unroll
  for (int mi = 0; mi < 4; ++mi)
#pragma unroll
    for (int ni = 0; ni < 4; ++ni)
      acc[mi][ni] = __builtin_amdgcn_mfma_f32_16x16x32_bf16(
          af[mi], bfr[ni], acc[mi][ni], 0, 0, 0);
}

DEVI void stage_bf16(const unsigned short* src, unsigned short* ls, int ld,
                     int tid) {
#pragma unroll
  for (int j = 0; j < 2; ++j) {
    int t = tid + j * 256, row = t >> 2, kk = (t & 3) << 3;
    async_load16(src + (size_t)row * ld + kk, ls + t * 8);
  }
}

// fp32 -> bf16 convert: xq|xk|xv -> Xb, Wq -> Wb, one dispatch
__global__ void cvt_all(const float* __restrict__ xq,
                        const float* __restrict__ xk,
                        const float* __restrict__ xv,
                        const float* __restrict__ Wq,
                        unsigned short* __restrict__ Xb,
                        unsigned short* __restrict__ Wb) {
  int i = blockIdx.x * blockDim.x + threadIdx.x;
  const float4* src;
  ushort4* dst;
  if (i < 3 * N4X) {
    int seg = i / N4X, off = i - seg * N4X;
    const float* s = (seg == 0) ? xq : (seg == 1) ? xk : xv;
    src = (const float4*)s + off;
    dst = (ushort4*)(Xb + (size_t)seg * 8192 * 1024) + off;
  } else {
    int off = i - 3 * N4X;  // [0, 1024*1024/4)
    src = (const float4*)Wq + off;
    dst = (ushort4*)Wb + off;
  }
  float4 v = *src;
  ushort4 o;
  o.x = f2b(v.x); o.y = f2b(v.y); o.z = f2b(v.z); o.w = f2b(v.w);
  *dst = o;
}

// ---------------------------------------------------------------------------
// QKV: C = Xb * Wb^T + bias.  Xb = [3*8192, 1024].  256x256 tiles, 384
// blocks.  XCD x gets gids [48x,48x+48): 12 consecutive 256-row A-panels x
// 4 bn (whole 2MB W + streamed A-panels resident per XCD L2).  V transposed.
// ---------------------------------------------------------------------------
__global__ __launch_bounds__(512, 2) void gemm_qkv(
    const unsigned short* __restrict__ Xb, const unsigned short* __restrict__ Wb,
    const float* __restrict__ bias, unsigned short* __restrict__ Qb,
    unsigned short* __restrict__ Kb, unsigned short* __restrict__ Vt) {
  __shared__ __align__(16) unsigned short lsA[2 * 256 * 64];
  __shared__ __align__(16) unsigned short lsB[2 * 256 * 64];
  const int l = blockIdx.x;
  const int gid = (l & 7) * 48 + (l >> 3);
  const int bn = gid & 3;               // 256-col tile
  const int bmg = gid >> 2;             // [0,96): 256-row tile
  const unsigned short* A = Xb + (size_t)bmg * 256 * 1024;
  const unsigned short* W = Wb + (size_t)bn * 256 * 1024;
  const int tid = threadIdx.x;

  floatx4 acc[8][4] = {};
  kloop256(A, 1024, W, 1024, 16, lsA, lsB, tid, acc);

  const int lane = tid & 63, wave = tid >> 6;
  const int wr = wave >> 2, wc = wave & 3;
  const int lrow = lane & 15, rb = (lane >> 4) * 4;
  const int input = bmg >> 5;  // 32 x 256-row tiles per input
  unsigned short* C = (input == 0) ? Qb : (input == 1) ? Kb : Vt;
  const int rowbase = (bmg & 31) * 256 + wr * 128;  // row within input
#pragma unroll
  for (int mi = 0; mi < 8; ++mi)
#pragma unroll
    for (int ni = 0; ni < 4; ++ni) {
      const int gcol = bn * 256 + wc * 64 + ni * 16 + lrow;
      const float bv = bias[gcol];
#pragma unroll
      for (int r = 0; r < 4; ++r) {
        const int grow = rowbase + mi * 16 + rb + r;
        const unsigned short val = f2b(acc[mi][ni][r] + bv);
        if (input == 2) {
          int b = grow >> 11, s = grow & 2047;
          C[((size_t)b * 1024 + gcol) * 2048 + s] = val;
        } else {
          C[(size_t)grow * 1024 + gcol] = val;
        }
      }
    }
}

// ---------------------------------------------------------------------------
// Scores+exp: P[z][q,k] = exp(Q.K/32) (unnorm bf16; 0 where k>q), row sums l
// via atomics.  256x256 lower-tri tiles: 36/batch, 144 blocks.
// ---------------------------------------------------------------------------
__global__ __launch_bounds__(512, 2) void gemm_scores_exp(
    const unsigned short* __restrict__ Qb,
    const unsigned short* __restrict__ Kb, unsigned short* __restrict__ P,
    float* __restrict__ lsum) {
  __shared__ __align__(16) unsigned short lsA[2 * 256 * 64];
  __shared__ __align__(16) unsigned short lsB[2 * 256 * 64];
  const int l = blockIdx.x;
  const int gid = (l & 7) * 18 + (l >> 3);  // [0,144)
  const int z = gid / 36;
  int r0 = gid % 36;
  int bm = 0;
  for (;;) { const int c = bm + 1; if (r0 < c) break; r0 -= c; ++bm; }
  const int bnn = r0;  // [0, bm]

  const unsigned short* A = Qb + ((size_t)z * S_ + bm * 256) * E_;
  const unsigned short* Bt = Kb + ((size_t)z * S_ + bnn * 256) * E_;
  const int tid = threadIdx.x;

  floatx4 acc[8][4] = {};
  kloop256(A, E_, Bt, E_, 16, lsA, lsB, tid, acc);

  const int lane = tid & 63, wave = tid >> 6;
  const int wr = wave >> 2, wc = wave & 3;
  const int lrow = lane & 15, rb = (lane >> 4) * 4;
  const bool diag = (bnn == bm);
#pragma unroll
  for (int mi = 0; mi < 8; ++mi)
#pragma unroll
    for (int r = 0; r < 4; ++r) {
      const int grow = bm * 256 + wr * 128 + mi * 16 + rb + r;
      float rsum = 0.f;
#pragma unroll
      for (int ni = 0; ni < 4; ++ni) {
        const int gcol = bnn * 256 + wc * 64 + ni * 16 + lrow;
        float p = __expf(acc[mi][ni][r] * 0.03125f);
        if (diag && gcol > grow) p = 0.f;
        P[((size_t)z * S_ + grow) * S_ + gcol] = f2b(p);
        rsum += p;
      }
#pragma unroll
      for (int off = 1; off < 16; off <<= 1) rsum += __shfl_xor(rsum, off);
      if ((lane & 15) == 0) atomicAdd(&lsum[z * S_ + grow], rsum);
    }
}

// ---------------------------------------------------------------------------
// PV (R5 verbatim): out[z][q,e] = (P V) / l[q], K truncated at (bm+1)*128.
// 512 blocks, pair-balanced: xcd handles bm in {15-xcd, xcd} for all 4 z.
// ---------------------------------------------------------------------------
__global__ __launch_bounds__(256) void gemm_pv(
    const unsigned short* __restrict__ Pb,
    const unsigned short* __restrict__ Vt, const float* __restrict__ lsum,
    float* __restrict__ Out) {
  __shared__ __align__(16) unsigned short lsA[2][128 * 32];
  __shared__ __align__(16) unsigned short lsB[2][128 * 32];
  const int l = blockIdx.x;
  const int xcd = l & 7, i = l >> 3;
  const int bn = i & 7, j = i >> 3;
  const int z = j >> 1;
  const int bm = (j & 1) ? xcd : 15 - xcd;

  const unsigned short* A = Pb + ((size_t)z * S_ + bm * 128) * S_;
  const unsigned short* Bt = Vt + ((size_t)z * E_ + bn * 128) * S_;
  float* C = Out + (size_t)z * S_ * E_;
  const int tid = threadIdx.x;
  const int lane = tid & 63, wave = tid >> 6;
  const int m0 = (wave >> 1) * 64, n0 = (wave & 1) * 64;
  const int lrow = lane & 15, lk = (lane >> 4) * 8;

  floatx4 acc[4][4] = {};
  const int nKK = (bm + 1) * 2;  // double-steps of 64 K
  for (int kt = 0; kt < nKK; ++kt) {
    if (kt) __syncthreads();
    stage_bf16(A + kt * 64, lsA[0], S_, tid);
    stage_bf16(A + kt * 64 + 32, lsA[1], S_, tid);
    stage_bf16(Bt + kt * 64, lsB[0], S_, tid);
    stage_bf16(Bt + kt * 64 + 32, lsB[1], S_, tid);
    __syncthreads();
    mfma_tile(lsA[0], lsB[0], m0, n0, lrow, lk, acc);
    mfma_tile(lsA[1], lsB[1], m0, n0, lrow, lk, acc);
  }

  const int rb = (lane >> 4) * 4;
#pragma unroll
  for (int mi = 0; mi < 4; ++mi)
#pragma unroll
    for (int r = 0; r < 4; ++r) {
      const int grow = bm * 128 + m0 + mi * 16 + rb + r;
      const float inv = 1.0f / lsum[z * S_ + grow];
#pragma unroll
      for (int ni = 0; ni < 4; ++ni) {
        const int gcol = bn * 128 + n0 + ni * 16 + lrow;
        C[(size_t)grow * E_ + gcol] = acc[mi][ni][r] * inv;
      }
    }
}

// ---------------------------------------------------------------------------
extern "C" void kernel_launch(void* const* d_in, const int* in_sizes, int n_in,
                              void* d_out, int out_size, void* d_ws,
                              size_t ws_size, hipStream_t stream) {
  (void)in_sizes; (void)n_in; (void)out_size; (void)ws_size;
  const float* xq = (const float*)d_in[0];
  const float* xk = (const float*)d_in[1];
  const float* xv = (const float*)d_in[2];
  const float* Wq = (const float*)d_in[3];
  const float* bq = (const float*)d_in[4];
  // d_in[5] att_mask: exact triu(k=1) causal mask, handled analytically.
  float* out = (float*)d_out;

  // workspace (<= 114 MB used):
  //  [0,48M):  Xb (bf16 3*8192*1024) during cvt+QKV; then reused as
  //            P (bf16 4*2048*2048 = 32M) by scores/pv.
  //  [48,50M): Wb  [50,66M): Qb  [66,82M): Kb  [82,98M): Vt
  //  [98M, 98M+32K): l (fp32 row sums)
  unsigned short* base16 = (unsigned short*)d_ws;
  unsigned short* Xb = base16;
  unsigned short* P = base16;
  unsigned short* Wb = base16 + (size_t)24 * 1024 * 1024;  // +48MB
  unsigned short* Qb = Wb + (size_t)1024 * 1024;
  unsigned short* Kb = Qb + (size_t)8192 * 1024;
  unsigned short* Vt = Kb + (size_t)8192 * 1024;
  float* lsum = (float*)(Vt + (size_t)8192 * 1024);  // +98MB, 32KB

  hipMemsetAsync(lsum, 0, BATCH * S_ * sizeof(float), stream);

  const int n4tot = 3 * N4X + 1024 * 1024 / 4;
  cvt_all<<<n4tot / 256, 256, 0, stream>>>(xq, xk, xv, Wq, Xb, Wb);

  gemm_qkv<<<384, 512, 0, stream>>>(Xb, Wb, bq, Qb, Kb, Vt);
  gemm_scores_exp<<<144, 512, 0, stream>>>(Qb, Kb, P, lsum);
  gemm_pv<<<512, 256, 0, stream>>>(P, Vt, lsum, out);
}

// Round 6
// 306.035 us; speedup vs baseline: 1.1455x; 1.1455x over previous
//
#include <hip/hip_runtime.h>
#include <hip/hip_bf16.h>
#include <stdint.h>

// ---------------------------------------------------------------------------
// HeadAttention: Q=xq*W^T+b, K=xk*W^T+b, V=xv*W^T+b (same W,b),
// O = softmax(causal(Q K^T / 32)) V.    B=4, S=2048, E=1024, fp32 in/out.
// R11 = R5 verbatim (grids, 256thr/4waves, 64x64 per wave, 2-barrier
// __syncthreads K-loop, epilogues) with ONE change: the LDS tile geometry.
//   Old: [2][128][32] linear 64B rows  -> measured 6.29M conflict cycles
//        (+4 cyc on every ds_read_b128; the LDS pipe is the saturated pipe).
//   New: [128][64] 128B rows, chunk c of row r at slot c^(r&7); linear
//        global_load_lds dest + inverse-swizzled per-lane source.  This
//        exact read pattern measured SQ_LDS_BANK_CONFLICT == 0 (R6/R8/R10):
//        every ds_read_b128 resolves in the minimum 8 bank-phases.
// Same 8 loads/thread/K-tile, same 32KB LDS, same occupancy (~5-6 blk/CU).
// ---------------------------------------------------------------------------

typedef __attribute__((ext_vector_type(8))) short bf16x8;
typedef __attribute__((ext_vector_type(4))) float floatx4;

#define DEVI static __device__ __forceinline__

static constexpr int S_ = 2048;
static constexpr int E_ = 1024;
static constexpr int BATCH = 4;
static constexpr int N4X = 8192 * 1024 / 4;  // float4 count per X input

DEVI unsigned short f2b(float f) {
  union { float f; unsigned u; } v; v.f = f;
  return (unsigned short)((v.u + 0x7FFFu + ((v.u >> 16) & 1u)) >> 16); // RNE
}

DEVI void async_load16(const void* g, void* l) {
  __builtin_amdgcn_global_load_lds(
      (__attribute__((address_space(1))) void*)(void*)(g),
      (__attribute__((address_space(3))) void*)(l),
      16, 0, 0);
}

// ---- zero-conflict 128x64 tile machinery (layout verified 0-conflict) -----

// stage a 128x64 bf16 tile (8 x 16B per thread, 256 threads).  LDS dest is
// linear (global_load_lds requirement); the 16B chunk at linear slot s of
// row r holds logical chunk s ^ (r&7) (source inverse-swizzled).
DEVI void stage64(const unsigned short* __restrict__ src, unsigned short* ls,
                  int ld, int tid) {
#pragma unroll
  for (int j = 0; j < 4; ++j) {
    const int u = tid + j * 256;
    const int row = u >> 3, slot = u & 7;
    async_load16(src + (size_t)row * ld + ((slot ^ (row & 7)) << 3),
                 ls + u * 8);
  }
}

// read logical (row r, k-chunk c in [0,8)) from a swizzled 128x64 tile
DEVI bf16x8 ldfrag64(const unsigned short* ls, int r, int c) {
  return *(const bf16x8*)(ls + r * 64 + ((c ^ (r & 7)) << 3));
}

// 32 MFMAs on one staged 128x64 A/B tile pair (two 32-K halves, same order
// as R5's two mfma_tile calls).  A/B frag elem j = Mat[16q+lrow][k0+8g+j].
DEVI void mfma_tile64(const unsigned short* lsA, const unsigned short* lsB,
                      int m0, int n0, int lrow, int g, floatx4 (&acc)[4][4]) {
#pragma unroll
  for (int ks = 0; ks < 2; ++ks) {
    bf16x8 af[4], bfr[4];
#pragma unroll
    for (int i = 0; i < 4; ++i)
      af[i] = ldfrag64(lsA, m0 + i * 16 + lrow, ks * 4 + g);
#pragma unroll
    for (int i = 0; i < 4; ++i)
      bfr[i] = ldfrag64(lsB, n0 + i * 16 + lrow, ks * 4 + g);
#pragma unroll
    for (int mi = 0; mi < 4; ++mi)
#pragma unroll
      for (int ni = 0; ni < 4; ++ni)
        acc[mi][ni] = __builtin_amdgcn_mfma_f32_16x16x32_bf16(
            af[mi], bfr[ni], acc[mi][ni], 0, 0, 0);
  }
}

// fp32 -> bf16 convert: xq|xk|xv -> Xb, Wq -> Wb, one dispatch
__global__ void cvt_all(const float* __restrict__ xq,
                        const float* __restrict__ xk,
                        const float* __restrict__ xv,
                        const float* __restrict__ Wq,
                        unsigned short* __restrict__ Xb,
                        unsigned short* __restrict__ Wb) {
  int i = blockIdx.x * blockDim.x + threadIdx.x;
  const float4* src;
  ushort4* dst;
  if (i < 3 * N4X) {
    int seg = i / N4X, off = i - seg * N4X;
    const float* s = (seg == 0) ? xq : (seg == 1) ? xk : xv;
    src = (const float4*)s + off;
    dst = (ushort4*)(Xb + (size_t)seg * 8192 * 1024) + off;
  } else {
    int off = i - 3 * N4X;  // [0, 1024*1024/4)
    src = (const float4*)Wq + off;
    dst = (ushort4*)Wb + off;
  }
  float4 v = *src;
  ushort4 o;
  o.x = f2b(v.x); o.y = f2b(v.y); o.z = f2b(v.z); o.w = f2b(v.w);
  *dst = o;
}

// ---------------------------------------------------------------------------
// Fused QKV linear: C = Xb * Wb^T + bias.  Xb = [3*8192, 1024].
// 1536 blocks; XCD swizzle: 8 bn sharing an A-tile at stride-8 => same XCD
// L2.  V (input 2) stored transposed: Vt[b][e][s].   (R5 mapping verbatim.)
// ---------------------------------------------------------------------------
__global__ __launch_bounds__(256) void gemm_qkv(
    const unsigned short* __restrict__ Xb, const unsigned short* __restrict__ Wb,
    const float* __restrict__ bias, unsigned short* __restrict__ Qb,
    unsigned short* __restrict__ Kb, unsigned short* __restrict__ Vt) {
  __shared__ __align__(16) unsigned short lsA[128 * 64];
  __shared__ __align__(16) unsigned short lsB[128 * 64];
  const int l = blockIdx.x;
  const int xcd = l & 7, i = l >> 3;
  const int bn = i & 7;
  const int bmg = xcd * 24 + (i >> 3);  // [0,192): global 128-row tile
  const int input = bmg / 64, bm = bmg % 64;
  const unsigned short* A = Xb + (size_t)bmg * 128 * 1024;
  const unsigned short* W = Wb + (size_t)bn * 128 * 1024;

  const int tid = threadIdx.x;
  const int lane = tid & 63, wave = tid >> 6;
  const int m0 = (wave >> 1) * 64, n0 = (wave & 1) * 64;
  const int lrow = lane & 15, g = lane >> 4;

  floatx4 acc[4][4] = {};
  for (int kt = 0; kt < 16; ++kt) {  // 16 barriers, 64 K each
    if (kt) __syncthreads();
    stage64(A + kt * 64, lsA, 1024, tid);
    stage64(W + kt * 64, lsB, 1024, tid);
    __syncthreads();
    mfma_tile64(lsA, lsB, m0, n0, lrow, g, acc);
  }

  unsigned short* C = (input == 0) ? Qb : (input == 1) ? Kb : Vt;
  const int rb = (lane >> 4) * 4;  // C/D: col=lane&15, row=(lane>>4)*4+reg
#pragma unroll
  for (int mi = 0; mi < 4; ++mi)
#pragma unroll
    for (int ni = 0; ni < 4; ++ni) {
      int gcol = bn * 128 + n0 + ni * 16 + lrow;
      float bv = bias[gcol];
#pragma unroll
      for (int r = 0; r < 4; ++r) {
        int grow = bm * 128 + m0 + mi * 16 + rb + r;
        unsigned short val = f2b(acc[mi][ni][r] + bv);
        if (input == 2) {
          int b = grow >> 11, s = grow & 2047;
          C[((size_t)b * 1024 + gcol) * 2048 + s] = val;
        } else {
          C[(size_t)grow * 1024 + gcol] = val;
        }
      }
    }
}

// ---------------------------------------------------------------------------
// Scores+exp: P[z][q,k] = exp(Q.K/32) (unnorm, bf16; 0 where k>q), and
// l[z*2048+q] += row sums (atomic).  Lower-tri 128-blocks only; swizzle: 768
// ids, 2 XCDs/batch, groups of 8 bn share a Q tile per XCD.  (R5 verbatim.)
// ---------------------------------------------------------------------------
__global__ __launch_bounds__(256) void gemm_scores_exp(
    const unsigned short* __restrict__ Qb,
    const unsigned short* __restrict__ Kb, unsigned short* __restrict__ P,
    float* __restrict__ lsum) {
  const int l = blockIdx.x;
  const int xcd = l & 7, k = l >> 3;
  const int m = k & 7, gl = k >> 3;
  const int gg = xcd * 12 + gl;
  const int z = gg / 24, r0 = gg % 24;
  const int bm = (r0 < 8) ? r0 : 8 + ((r0 - 8) >> 1);
  const int bn = ((r0 < 8) ? 0 : ((r0 - 8) & 1)) * 8 + m;
  if (bn > bm) return;

  __shared__ __align__(16) unsigned short lsA[128 * 64];
  __shared__ __align__(16) unsigned short lsB[128 * 64];
  const unsigned short* A = Qb + ((size_t)z * S_ + bm * 128) * E_;
  const unsigned short* Bt = Kb + ((size_t)z * S_ + bn * 128) * E_;
  const int tid = threadIdx.x;
  const int lane = tid & 63, wave = tid >> 6;
  const int m0 = (wave >> 1) * 64, n0 = (wave & 1) * 64;
  const int lrow = lane & 15, g = lane >> 4;

  floatx4 acc[4][4] = {};
  for (int kt = 0; kt < 16; ++kt) {
    if (kt) __syncthreads();
    stage64(A + kt * 64, lsA, E_, tid);
    stage64(Bt + kt * 64, lsB, E_, tid);
    __syncthreads();
    mfma_tile64(lsA, lsB, m0, n0, lrow, g, acc);
  }

  const int rb = (lane >> 4) * 4;
  const bool diag = (bm == bn);
#pragma unroll
  for (int mi = 0; mi < 4; ++mi)
#pragma unroll
    for (int r = 0; r < 4; ++r) {
      const int grow = bm * 128 + m0 + mi * 16 + rb + r;
      float rsum = 0.f;
#pragma unroll
      for (int ni = 0; ni < 4; ++ni) {
        const int gcol = bn * 128 + n0 + ni * 16 + lrow;
        float p = __expf(acc[mi][ni][r] * 0.03125f);
        if (diag && gcol > grow) p = 0.f;
        P[((size_t)z * S_ + grow) * S_ + gcol] = f2b(p);
        rsum += p;
      }
      // reduce over the 16 lanes holding this row's 64 columns
#pragma unroll
      for (int off = 1; off < 16; off <<= 1) rsum += __shfl_xor(rsum, off);
      if ((lane & 15) == 0) atomicAdd(&lsum[z * S_ + grow], rsum);
    }
}

// ---------------------------------------------------------------------------
// PV: out[z][q,e] = (P V) / l[q], K truncated at (bm+1)*128.
// 512 blocks, pair-balanced: xcd handles bm in {15-xcd, xcd} for all 4 z;
// 8 bn per row-tile share the P tile on one XCD.  (R5 mapping verbatim.)
// ---------------------------------------------------------------------------
__global__ __launch_bounds__(256) void gemm_pv(
    const unsigned short* __restrict__ Pb,
    const unsigned short* __restrict__ Vt, const float* __restrict__ lsum,
    float* __restrict__ Out) {
  __shared__ __align__(16) unsigned short lsA[128 * 64];
  __shared__ __align__(16) unsigned short lsB[128 * 64];
  const int l = blockIdx.x;
  const int xcd = l & 7, i = l >> 3;
  const int bn = i & 7, j = i >> 3;
  const int z = j >> 1;
  const int bm = (j & 1) ? xcd : 15 - xcd;

  const unsigned short* A = Pb + ((size_t)z * S_ + bm * 128) * S_;
  const unsigned short* Bt = Vt + ((size_t)z * E_ + bn * 128) * S_;
  float* C = Out + (size_t)z * S_ * E_;
  const int tid = threadIdx.x;
  const int lane = tid & 63, wave = tid >> 6;
  const int m0 = (wave >> 1) * 64, n0 = (wave & 1) * 64;
  const int lrow = lane & 15, g = lane >> 4;

  floatx4 acc[4][4] = {};
  const int nKK = (bm + 1) * 2;  // 64-K steps, covers k <= bm*128+127
  for (int kt = 0; kt < nKK; ++kt) {
    if (kt) __syncthreads();
    stage64(A + kt * 64, lsA, S_, tid);
    stage64(Bt + kt * 64, lsB, S_, tid);
    __syncthreads();
    mfma_tile64(lsA, lsB, m0, n0, lrow, g, acc);
  }

  const int rb = (lane >> 4) * 4;
#pragma unroll
  for (int mi = 0; mi < 4; ++mi)
#pragma unroll
    for (int r = 0; r < 4; ++r) {
      const int grow = bm * 128 + m0 + mi * 16 + rb + r;
      const float inv = 1.0f / lsum[z * S_ + grow];
#pragma unroll
      for (int ni = 0; ni < 4; ++ni) {
        const int gcol = bn * 128 + n0 + ni * 16 + lrow;
        C[(size_t)grow * E_ + gcol] = acc[mi][ni][r] * inv;
      }
    }
}

// ---------------------------------------------------------------------------
extern "C" void kernel_launch(void* const* d_in, const int* in_sizes, int n_in,
                              void* d_out, int out_size, void* d_ws,
                              size_t ws_size, hipStream_t stream) {
  (void)in_sizes; (void)n_in; (void)out_size; (void)ws_size;
  const float* xq = (const float*)d_in[0];
  const float* xk = (const float*)d_in[1];
  const float* xv = (const float*)d_in[2];
  const float* Wq = (const float*)d_in[3];
  const float* bq = (const float*)d_in[4];
  // d_in[5] att_mask: exact triu(k=1) causal mask, handled analytically.
  float* out = (float*)d_out;

  // workspace (<= 114 MB used):
  //  [0,48M):  Xb (bf16 3*8192*1024) during cvt+QKV; then reused as
  //            P (bf16 4*2048*2048 = 32M) by scores/pv.
  //  [48,50M): Wb  [50,66M): Qb  [66,82M): Kb  [82,98M): Vt
  //  [98M, 98M+32K): l (fp32 row sums)
  unsigned short* base16 = (unsigned short*)d_ws;
  unsigned short* Xb = base16;
  unsigned short* P = base16;
  unsigned short* Wb = base16 + (size_t)24 * 1024 * 1024;  // +48MB
  unsigned short* Qb = Wb + (size_t)1024 * 1024;
  unsigned short* Kb = Qb + (size_t)8192 * 1024;
  unsigned short* Vt = Kb + (size_t)8192 * 1024;
  float* lsum = (float*)(Vt + (size_t)8192 * 1024);  // +98MB, 32KB

  hipMemsetAsync(lsum, 0, BATCH * S_ * sizeof(float), stream);

  const int n4tot = 3 * N4X + 1024 * 1024 / 4;
  cvt_all<<<n4tot / 256, 256, 0, stream>>>(xq, xk, xv, Wq, Xb, Wb);

  gemm_qkv<<<1536, 256, 0, stream>>>(Xb, Wb, bq, Qb, Kb, Vt);
  gemm_scores_exp<<<768, 256, 0, stream>>>(Qb, Kb, P, lsum);
  gemm_pv<<<512, 256, 0, stream>>>(P, Vt, lsum, out);
}